// Round 4
// baseline (167.632 us; speedup 1.0000x reference)
//
#include <hip/hip_runtime.h>

#define BB 32
#define MM 512
#define SS 10
#define VV 32000
#define DD 128
#define HOPS 3
#define BM (BB * MM)

// K3 partitioning: 500 blocks x 64 vocab rows
#define NP3 500
#define VPB (VV / NP3)   // 64

// ====================== PRIMARY PATH (histogram / dual-GEMV) ======================

// K1: cu[v][b] = dot(A[v,:], uin[b,:]) for all v,b.  Also zeroes hist and den.
// 4 threads per v, each owns 8 consecutive b. grid = 500 x 256.
__global__ __launch_bounds__(256) void gemv_cu(const float* __restrict__ A,
                                               const float* __restrict__ uin,
                                               float* __restrict__ cu,
                                               float* __restrict__ hist,
                                               float* __restrict__ den) {
    __shared__ float su[BB * DD];
    const int tid = threadIdx.x;
    for (int i = tid; i < BB * DD; i += 256) su[i] = uin[i];
    __syncthreads();

    const int gid = blockIdx.x * 256 + tid;          // 0 .. 127999
    const int v = gid >> 2;
    const int b0 = (gid & 3) * 8;

    float acc[8] = {0.f, 0.f, 0.f, 0.f, 0.f, 0.f, 0.f, 0.f};
    const float4* Ar = (const float4*)(A + (size_t)v * DD);
#pragma unroll 4
    for (int d4 = 0; d4 < DD / 4; ++d4) {
        const float4 a = Ar[d4];
#pragma unroll
        for (int j = 0; j < 8; ++j) {
            const float4 uu = ((const float4*)(su + (b0 + j) * DD))[d4];
            acc[j] += a.x * uu.x + a.y * uu.y + a.z * uu.z + a.w * uu.w;
        }
    }
    float* dst = cu + (size_t)v * BB + b0;
    ((float4*)dst)[0] = make_float4(acc[0], acc[1], acc[2], acc[3]);
    ((float4*)dst)[1] = make_float4(acc[4], acc[5], acc[6], acc[7]);
    float* hz = hist + (size_t)v * BB + b0;
    ((float4*)hz)[0] = make_float4(0.f, 0.f, 0.f, 0.f);
    ((float4*)hz)[1] = make_float4(0.f, 0.f, 0.f, 0.f);
    if (gid < BB) den[gid] = 0.f;
}

// K2: per (b,m): l = sum_s cu[tok][b]; e = exp(l) (max-free); scatter e into hist,den.
// grid = 128 x 128; a block spans 128 consecutive m of one b.
template <int WRITE_LOGIT>
__global__ __launch_bounds__(128) void scatter_w(const int* __restrict__ story,
                                                 const float* __restrict__ cu,
                                                 float* __restrict__ hist,
                                                 float* __restrict__ den,
                                                 float* __restrict__ logit) {
    const int bm = blockIdx.x * 128 + threadIdx.x;
    const int b = bm >> 9;
    const int* st = story + (size_t)bm * SS;
    int tok[SS];
#pragma unroll
    for (int s = 0; s < SS; ++s) tok[s] = st[s];
    float l = 0.f;
#pragma unroll
    for (int s = 0; s < SS; ++s) l += cu[(size_t)tok[s] * BB + b];
    if (WRITE_LOGIT) logit[bm] = l;
    const float e = expf(l);
#pragma unroll
    for (int s = 0; s < SS; ++s) unsafeAtomicAdd(&hist[(size_t)tok[s] * BB + b], e);
    float sv = e;
#pragma unroll
    for (int off = 32; off; off >>= 1) sv += __shfl_xor(sv, off, 64);
    if ((threadIdx.x & 63) == 0) unsafeAtomicAdd(&den[b], sv);
}

// K3: P[blk][b][d] = sum_{v in 64-row chunk} hist[v][b] * Cn[v][d].
// block = 4 waves; wave handles v stride-4; lane covers d = 2l, 2l+1.
__global__ __launch_bounds__(256) void hist_gemm(const float* __restrict__ Cn,
                                                 const float* __restrict__ hist,
                                                 float* __restrict__ P) {
    __shared__ float smem[3 * BB * DD];   // 12288 floats; first VPB*BB used for hist stage
    const int tid = threadIdx.x, w = tid >> 6, lane = tid & 63;
    const int v0 = blockIdx.x * VPB;

    for (int i = tid; i < VPB * BB; i += 256) smem[i] = hist[(size_t)v0 * BB + i];
    __syncthreads();

    float2 acc[BB];
#pragma unroll
    for (int b = 0; b < BB; ++b) acc[b] = make_float2(0.f, 0.f);

    for (int vl = w; vl < VPB; vl += 4) {
        const float2 c = ((const float2*)(Cn + (size_t)(v0 + vl) * DD))[lane];
#pragma unroll
        for (int b = 0; b < BB; ++b) {
            const float h = smem[vl * BB + b];
            acc[b].x += h * c.x;
            acc[b].y += h * c.y;
        }
    }
    __syncthreads();
    if (w > 0) {
        float* dst = smem + (w - 1) * (BB * DD);
#pragma unroll
        for (int b = 0; b < BB; ++b) {
            dst[b * DD + 2 * lane]     = acc[b].x;
            dst[b * DD + 2 * lane + 1] = acc[b].y;
        }
    }
    __syncthreads();
    if (w == 0) {
        float* Pb = P + (size_t)blockIdx.x * (BB * DD);
#pragma unroll
        for (int b = 0; b < BB; ++b) {
            float x = acc[b].x, y = acc[b].y;
#pragma unroll
            for (int ww = 0; ww < 3; ++ww) {
                x += smem[ww * (BB * DD) + b * DD + 2 * lane];
                y += smem[ww * (BB * DD) + b * DD + 2 * lane + 1];
            }
            ((float2*)(Pb + b * DD))[lane] = make_float2(x, y);
        }
    }
}

// K4: uout[b][d] = ubase[b][d] + (sum_np P[np][b][d]) / den[b]
// grid = 32 x 512; 4 np-quarters per d, LDS combine.
__global__ __launch_bounds__(512) void reduce_u(const float* __restrict__ P,
                                                const float* __restrict__ ubase,
                                                const float* __restrict__ den,
                                                float* __restrict__ uout) {
    __shared__ float red[512];
    const int b = blockIdx.x;
    const int d = threadIdx.x & 127;
    const int q = threadIdx.x >> 7;      // np quarter
    const int i = b * DD + d;
    float s = 0.f;
#pragma unroll 5
    for (int np = q * (NP3 / 4); np < (q + 1) * (NP3 / 4); ++np)
        s += P[(size_t)np * (BB * DD) + i];
    red[threadIdx.x] = s;
    __syncthreads();
    if (q == 0) {
        s = red[d] + red[128 + d] + red[256 + d] + red[384 + d];
        uout[i] = ubase[i] + s / den[b];
    }
}

// ====================== FALLBACK PATH (round-1, known-good) ======================
__global__ __launch_bounds__(256) void init_u(const float* __restrict__ hidden,
                                              float* __restrict__ u) {
    int i = blockIdx.x * 256 + threadIdx.x;
    if (i < BB * DD) u[i] = hidden[i];
}

__global__ __launch_bounds__(256) void logit_kernel(const int* __restrict__ story,
                                                    const float* __restrict__ Ch,
                                                    const float* __restrict__ u,
                                                    float* __restrict__ logit) {
    int wid = (blockIdx.x * 256 + threadIdx.x) >> 6;
    int lane = threadIdx.x & 63;
    if (wid >= BB * MM) return;
    int b = wid >> 9;
    const int* st = story + (size_t)wid * SS;
    int tok[SS];
#pragma unroll
    for (int s = 0; s < SS; ++s) tok[s] = st[s];
    float ax = 0.f, ay = 0.f;
#pragma unroll
    for (int s = 0; s < SS; ++s) {
        const float2 v = ((const float2*)(Ch + (size_t)tok[s] * DD))[lane];
        ax += v.x; ay += v.y;
    }
    const float2 uv = ((const float2*)(u + b * DD))[lane];
    float p = ax * uv.x + ay * uv.y;
#pragma unroll
    for (int off = 32; off; off >>= 1) p += __shfl_down(p, off, 64);
    if (lane == 0) logit[wid] = p;
}

__global__ __launch_bounds__(256) void softmax_kernel(const float* __restrict__ logit,
                                                      float* __restrict__ prob) {
    int b = blockIdx.x;
    int t = threadIdx.x;
    __shared__ float red[8];
    float l0 = logit[b * MM + t];
    float l1 = logit[b * MM + 256 + t];
    float mx = fmaxf(l0, l1);
#pragma unroll
    for (int off = 32; off; off >>= 1) mx = fmaxf(mx, __shfl_xor(mx, off, 64));
    if ((t & 63) == 0) red[t >> 6] = mx;
    __syncthreads();
    mx = fmaxf(fmaxf(red[0], red[1]), fmaxf(red[2], red[3]));
    float e0 = expf(l0 - mx), e1 = expf(l1 - mx);
    float s = e0 + e1;
#pragma unroll
    for (int off = 32; off; off >>= 1) s += __shfl_xor(s, off, 64);
    if ((t & 63) == 0) red[4 + (t >> 6)] = s;
    __syncthreads();
    s = red[4] + red[5] + red[6] + red[7];
    float inv = 1.0f / s;
    prob[b * MM + t] = e0 * inv;
    prob[b * MM + 256 + t] = e1 * inv;
}

__global__ __launch_bounds__(256) void partial_kernel(const int* __restrict__ story,
                                                      const float* __restrict__ Ch1,
                                                      const float* __restrict__ prob,
                                                      float* __restrict__ partial,
                                                      int chunk) {
    int b = blockIdx.y, c = blockIdx.x;
    int w = threadIdx.x >> 6, lane = threadIdx.x & 63;
    int m0 = c * chunk;
    float ax = 0.f, ay = 0.f;
    for (int m = m0 + w; m < m0 + chunk; m += 4) {
        float pw = prob[b * MM + m];
        const int* st = story + (size_t)(b * MM + m) * SS;
        int tok[SS];
#pragma unroll
        for (int s = 0; s < SS; ++s) tok[s] = st[s];
        float sx = 0.f, sy = 0.f;
#pragma unroll
        for (int s = 0; s < SS; ++s) {
            const float2 v = ((const float2*)(Ch1 + (size_t)tok[s] * DD))[lane];
            sx += v.x; sy += v.y;
        }
        ax += pw * sx; ay += pw * sy;
    }
    __shared__ float redx[4][64];
    __shared__ float redy[4][64];
    redx[w][lane] = ax;
    redy[w][lane] = ay;
    __syncthreads();
    if (w == 0) {
        float ox = redx[0][lane] + redx[1][lane] + redx[2][lane] + redx[3][lane];
        float oy = redy[0][lane] + redy[1][lane] + redy[2][lane] + redy[3][lane];
        float2* dst = (float2*)(partial + ((size_t)b * gridDim.x + c) * DD);
        dst[lane] = make_float2(ox, oy);
    }
}

__global__ __launch_bounds__(256) void update_kernel(const float* __restrict__ partial,
                                                     float* __restrict__ u, int NC) {
    int i = blockIdx.x * 256 + threadIdx.x;
    if (i >= BB * DD) return;
    int b = i >> 7, d = i & 127;
    float s = 0.f;
    for (int c = 0; c < NC; ++c) s += partial[((size_t)b * NC + c) * DD + d];
    u[i] += s;
}

extern "C" void kernel_launch(void* const* d_in, const int* in_sizes, int n_in,
                              void* d_out, int out_size, void* d_ws, size_t ws_size,
                              hipStream_t stream) {
    const int*   story  = (const int*)d_in[0];
    const float* hidden = (const float*)d_in[1];
    const float* Cmat   = (const float*)d_in[2];

    float* out   = (float*)d_out;
    float* logit = out;              // final prob_logit [B,M]
    float* uout  = out + BB * MM;    // final u [B,D]

    // ws layout (floats): cu | hist | P | den | ub1 | ub2
    const size_t szCU = (size_t)VV * BB;          // 1.024M
    const size_t szP  = (size_t)NP3 * BB * DD;    // 2.048M
    const size_t need = (2 * szCU + szP + 32 + 2 * BB * DD) * sizeof(float);

    if (ws_size >= need) {
        float* cu   = (float*)d_ws;
        float* hist = cu + szCU;
        float* P    = hist + szCU;
        float* den  = P + szP;
        float* ub1  = den + 32;
        float* ub2  = ub1 + BB * DD;

        const float* C0 = Cmat;
        const float* C1 = Cmat + (size_t)1 * VV * DD;
        const float* C2 = Cmat + (size_t)2 * VV * DD;
        const float* C3 = Cmat + (size_t)3 * VV * DD;

        // hop 0
        gemv_cu<<<NP3, 256, 0, stream>>>(C0, hidden, cu, hist, den);
        scatter_w<0><<<BM / 128, 128, 0, stream>>>(story, cu, hist, den, nullptr);
        hist_gemm<<<NP3, 256, 0, stream>>>(C1, hist, P);
        reduce_u<<<BB, 512, 0, stream>>>(P, hidden, den, ub1);
        // hop 1
        gemv_cu<<<NP3, 256, 0, stream>>>(C1, ub1, cu, hist, den);
        scatter_w<0><<<BM / 128, 128, 0, stream>>>(story, cu, hist, den, nullptr);
        hist_gemm<<<NP3, 256, 0, stream>>>(C2, hist, P);
        reduce_u<<<BB, 512, 0, stream>>>(P, ub1, den, ub2);
        // hop 2
        gemv_cu<<<NP3, 256, 0, stream>>>(C2, ub2, cu, hist, den);
        scatter_w<1><<<BM / 128, 128, 0, stream>>>(story, cu, hist, den, logit);
        hist_gemm<<<NP3, 256, 0, stream>>>(C3, hist, P);
        reduce_u<<<BB, 512, 0, stream>>>(P, ub2, den, uout);
    } else {
        float* prob = (float*)d_ws;
        int NC = 32;
        while (NC > 1 && (size_t)(BB * MM + BB * NC * DD) * 4 > ws_size) NC >>= 1;
        float* partial = prob + BB * MM;
        int chunk = MM / NC;

        init_u<<<(BB * DD + 255) / 256, 256, 0, stream>>>(hidden, uout);
        for (int h = 0; h < HOPS; ++h) {
            const float* Ca = Cmat + (size_t)h * VV * DD;
            const float* Cc = Cmat + (size_t)(h + 1) * VV * DD;
            logit_kernel<<<(BB * MM) / 4, 256, 0, stream>>>(story, Ca, uout, logit);
            softmax_kernel<<<BB, 256, 0, stream>>>(logit, prob);
            partial_kernel<<<dim3(NC, BB), 256, 0, stream>>>(story, Cc, prob, partial, chunk);
            update_kernel<<<(BB * DD + 255) / 256, 256, 0, stream>>>(partial, uout, NC);
        }
    }
}